// Round 1
// baseline (1331.951 us; speedup 1.0000x reference)
//
#include <hip/hip_runtime.h>

#define N_NODES 50000
#define N_EDGES 800000
#define N_GRAPHS 512
#define F_IN 128
#define HDIM 96
#define NCLS 10
#define BN_EPS 1e-5f

// ---------------- column stats (sum, sumsq) over rows ----------------
template<int NC>
__global__ __launch_bounds__(2*NC) void colstats_kernel(const float* __restrict__ in,
                                                        float* __restrict__ stats,
                                                        int nrows) {
    const int col  = threadIdx.x % NC;
    const int half = threadIdx.x / NC;
    float s = 0.f, ss = 0.f;
    for (int r = blockIdx.x * 2 + half; r < nrows; r += gridDim.x * 2) {
        float v = in[(size_t)r * NC + col];
        s += v; ss += v * v;
    }
    __shared__ float shs[2][NC], shq[2][NC];
    shs[half][col] = s; shq[half][col] = ss;
    __syncthreads();
    if (half == 0) {
        atomicAdd(&stats[col],      s  + shs[1][col]);
        atomicAdd(&stats[NC + col], ss + shq[1][col]);
    }
}

// stats -> per-column affine (a = w*rsqrt(var+eps), c = b - mu*a)
__global__ void finalize_bn_kernel(const float* __restrict__ stats,
                                   const float* __restrict__ w,
                                   const float* __restrict__ b,
                                   float* __restrict__ ac, int ncols, float inv_n) {
    int k = blockIdx.x * blockDim.x + threadIdx.x;
    if (k < ncols) {
        float mu  = stats[k] * inv_n;
        float var = stats[ncols + k] * inv_n - mu * mu;
        float a   = w[k] * rsqrtf(var + BN_EPS);
        ac[k]         = a;
        ac[ncols + k] = b[k] - mu * a;
    }
}

// ---------------- CSR build (by dst) ----------------
__global__ void hist_kernel(const int* __restrict__ dst, int* __restrict__ deg, int ne) {
    int e = blockIdx.x * blockDim.x + threadIdx.x;
    if (e < ne) atomicAdd(&deg[dst[e]], 1);
}

__global__ __launch_bounds__(1024) void scan_kernel(const int* __restrict__ deg,
                                                    int* __restrict__ row_ptr,
                                                    int* __restrict__ cursor, int n) {
    __shared__ int sh[1024];
    const int tid = threadIdx.x;
    const int chunk = (n + 1023) / 1024;
    const int lo = tid * chunk;
    const int hi = min(lo + chunk, n);
    int s = 0;
    for (int i = lo; i < hi; i++) s += deg[i];
    sh[tid] = s;
    __syncthreads();
    for (int off = 1; off < 1024; off <<= 1) {
        int v = 0;
        if (tid >= off) v = sh[tid - off];
        __syncthreads();
        if (tid >= off) sh[tid] += v;
        __syncthreads();
    }
    int run = (tid == 0) ? 0 : sh[tid - 1];
    for (int i = lo; i < hi; i++) {
        row_ptr[i] = run; cursor[i] = run;
        run += deg[i];
    }
    if (tid == 1023) row_ptr[n] = sh[1023];
}

__global__ void fill_kernel(const int* __restrict__ src, const int* __restrict__ dst,
                            int* __restrict__ cursor, int* __restrict__ csr_src, int ne) {
    int e = blockIdx.x * blockDim.x + threadIdx.x;
    if (e < ne) {
        int pos = atomicAdd(&cursor[dst[e]], 1);
        csr_src[pos] = src[e];
    }
}

// ---------------- GIN aggregation: m[n] = h[n] + sum_{s in nbr(n)} h[s] ----------------
__global__ __launch_bounds__(192) void agg_kernel(const float* __restrict__ h,
                                                  const int* __restrict__ row_ptr,
                                                  const int* __restrict__ csr_src,
                                                  float* __restrict__ m, int n) {
    const int j    = threadIdx.x % HDIM;
    const int node = blockIdx.x * 2 + threadIdx.x / HDIM;
    if (node >= n) return;
    const int p0 = row_ptr[node], p1 = row_ptr[node + 1];
    float acc = h[(size_t)node * HDIM + j];
    for (int p = p0; p < p1; p++) {
        int s = csr_src[p];
        acc += h[(size_t)s * HDIM + j];
    }
    m[(size_t)node * HDIM + j] = acc;
}

// ---------------- fused matmul: out = [opt relu][opt BN-affine](in) @ W + bias ----------------
// optional output relu, optional fused column-stats of the output.
template<int KDIM, bool IN_AFF, bool IN_RELU, bool OUT_RELU, bool STATS>
__global__ __launch_bounds__(192) void mm_kernel(const float* __restrict__ in,
                                                 const float* __restrict__ W,
                                                 const float* __restrict__ bias,
                                                 const float* __restrict__ ac,
                                                 float* __restrict__ out,
                                                 float* __restrict__ stats, int nrows) {
    __shared__ float ws[KDIM][HDIM];
    __shared__ float xs[8][KDIM];
    __shared__ float shs[2][HDIM], shq[2][HDIM];
    const int tid = threadIdx.x;
    for (int i = tid; i < KDIM * HDIM; i += 192) ws[i / HDIM][i % HDIM] = W[i];
    const int row0 = blockIdx.x * 8;
    for (int i = tid; i < 8 * KDIM; i += 192) {
        int r = i / KDIM, k = i % KDIM;
        int gr = row0 + r;
        float v = (gr < nrows) ? in[(size_t)gr * KDIM + k] : 0.f;
        if constexpr (IN_AFF)  v = v * ac[k] + ac[KDIM + k];
        if constexpr (IN_RELU) v = fmaxf(v, 0.f);
        xs[r][k] = v;
    }
    __syncthreads();
    const int j    = tid % HDIM;
    const int half = tid / HDIM;           // 0 or 1; rows half, half+2, half+4, half+6
    const float bj = bias[j];
    float a0 = bj, a1 = bj, a2 = bj, a3 = bj;
    #pragma unroll 4
    for (int k = 0; k < KDIM; k++) {
        float wkj = ws[k][j];
        a0 = fmaf(xs[half    ][k], wkj, a0);
        a1 = fmaf(xs[half + 2][k], wkj, a1);
        a2 = fmaf(xs[half + 4][k], wkj, a2);
        a3 = fmaf(xs[half + 6][k], wkj, a3);
    }
    if constexpr (OUT_RELU) {
        a0 = fmaxf(a0, 0.f); a1 = fmaxf(a1, 0.f);
        a2 = fmaxf(a2, 0.f); a3 = fmaxf(a3, 0.f);
    }
    float s = 0.f, ss = 0.f;
    int r;
    r = row0 + half;     if (r < nrows) { out[(size_t)r * HDIM + j] = a0; s += a0; ss += a0 * a0; }
    r = row0 + half + 2; if (r < nrows) { out[(size_t)r * HDIM + j] = a1; s += a1; ss += a1 * a1; }
    r = row0 + half + 4; if (r < nrows) { out[(size_t)r * HDIM + j] = a2; s += a2; ss += a2 * a2; }
    r = row0 + half + 6; if (r < nrows) { out[(size_t)r * HDIM + j] = a3; s += a3; ss += a3 * a3; }
    if constexpr (STATS) {
        shs[half][j] = s; shq[half][j] = ss;
        __syncthreads();
        if (half == 0) {
            atomicAdd(&stats[j],        s  + shs[1][j]);
            atomicAdd(&stats[HDIM + j], ss + shq[1][j]);
        }
    }
}

// ---------------- global add pool ----------------
__global__ void pool_kernel(const float* __restrict__ h, const int* __restrict__ batch,
                            float* __restrict__ g, int n) {
    int idx = blockIdx.x * blockDim.x + threadIdx.x;
    if (idx < n * HDIM) {
        int node = idx / HDIM, j = idx % HDIM;
        atomicAdd(&g[(size_t)batch[node] * HDIM + j], h[idx]);
    }
}

// ---------------- head: logits = BN(g1) @ Wc + bc, then log_softmax ----------------
__global__ void head_kernel(const float* __restrict__ g1, const float* __restrict__ ac,
                            const float* __restrict__ Wc, const float* __restrict__ bc,
                            float* __restrict__ out, int ngraphs) {
    int gi = blockIdx.x * blockDim.x + threadIdx.x;
    if (gi >= ngraphs) return;
    float v[NCLS];
    #pragma unroll
    for (int c = 0; c < NCLS; c++) v[c] = bc[c];
    for (int k = 0; k < HDIM; k++) {
        float x = g1[(size_t)gi * HDIM + k] * ac[k] + ac[HDIM + k];
        #pragma unroll
        for (int c = 0; c < NCLS; c++) v[c] = fmaf(x, Wc[k * NCLS + c], v[c]);
    }
    float mx = v[0];
    #pragma unroll
    for (int c = 1; c < NCLS; c++) mx = fmaxf(mx, v[c]);
    float sum = 0.f;
    #pragma unroll
    for (int c = 0; c < NCLS; c++) sum += expf(v[c] - mx);
    float lse = mx + logf(sum);
    #pragma unroll
    for (int c = 0; c < NCLS; c++) out[(size_t)gi * NCLS + c] = v[c] - lse;
}

extern "C" void kernel_launch(void* const* d_in, const int* in_sizes, int n_in,
                              void* d_out, int out_size, void* d_ws, size_t ws_size,
                              hipStream_t stream) {
    const float* x         = (const float*)d_in[0];
    const int*   ei        = (const int*)  d_in[1];
    const int*   batch     = (const int*)  d_in[2];
    const float* bn_feat_w = (const float*)d_in[3];
    const float* bn_feat_b = (const float*)d_in[4];
    const float* Wf        = (const float*)d_in[5];
    const float* bfv       = (const float*)d_in[6];
    const float* bn_fc_w   = (const float*)d_in[7];
    const float* bn_fc_b   = (const float*)d_in[8];
    const float* Wl        = (const float*)d_in[9];
    const float* bl        = (const float*)d_in[10];
    const float* bn_hid_w  = (const float*)d_in[11];
    const float* bn_hid_b  = (const float*)d_in[12];
    const float* Wc        = (const float*)d_in[13];
    const float* bc        = (const float*)d_in[14];
    float* out = (float*)d_out;

    char* p = (char*)d_ws;
    auto alloc = [&](size_t bytes) { char* q = p; p += (bytes + 255) & ~(size_t)255; return q; };
    float* h      = (float*)alloc((size_t)N_NODES * HDIM * 4);
    float* buf    = (float*)alloc((size_t)N_NODES * HDIM * 4);
    float* g      = (float*)alloc((size_t)N_GRAPHS * HDIM * 4);
    float* g1     = (float*)alloc((size_t)N_GRAPHS * HDIM * 4);
    float* statsX = (float*)alloc(2 * F_IN * 4);
    float* acX    = (float*)alloc(2 * F_IN * 4);
    float* statsT = (float*)alloc(2 * HDIM * 4);
    float* acT    = (float*)alloc(2 * HDIM * 4);
    float* statsG = (float*)alloc(2 * HDIM * 4);
    float* acG    = (float*)alloc(2 * HDIM * 4);
    float* statsG1= (float*)alloc(2 * HDIM * 4);
    float* acHid  = (float*)alloc(2 * HDIM * 4);
    int* deg      = (int*)alloc((size_t)N_NODES * 4);
    int* row_ptr  = (int*)alloc((size_t)(N_NODES + 1) * 4);
    int* cursor   = (int*)alloc((size_t)N_NODES * 4);
    int* csr      = (int*)alloc((size_t)N_EDGES * 4);

    const int* srcp = ei;
    const int* dstp = ei + N_EDGES;

    // BN(x) stats, then h = relu(BN(x) @ Wf + bf)
    hipMemsetAsync(statsX, 0, 2 * F_IN * 4, stream);
    colstats_kernel<F_IN><<<256, 2 * F_IN, 0, stream>>>(x, statsX, N_NODES);
    finalize_bn_kernel<<<1, F_IN, 0, stream>>>(statsX, bn_feat_w, bn_feat_b, acX, F_IN, 1.0f / N_NODES);
    mm_kernel<F_IN, true, false, true, false><<<N_NODES / 8, 192, 0, stream>>>(x, Wf, bfv, acX, h, nullptr, N_NODES);

    // CSR build (once; reused by all 3 layers)
    hipMemsetAsync(deg, 0, (size_t)N_NODES * 4, stream);
    hist_kernel<<<(N_EDGES + 255) / 256, 256, 0, stream>>>(dstp, deg, N_EDGES);
    scan_kernel<<<1, 1024, 0, stream>>>(deg, row_ptr, cursor, N_NODES);
    fill_kernel<<<(N_EDGES + 255) / 256, 256, 0, stream>>>(srcp, dstp, cursor, csr, N_EDGES);

    for (int l = 0; l < 3; l++) {
        const float* W1 = (const float*)d_in[15 + 6 * l];
        const float* b1 = (const float*)d_in[16 + 6 * l];
        const float* bw = (const float*)d_in[17 + 6 * l];
        const float* bb = (const float*)d_in[18 + 6 * l];
        const float* W2 = (const float*)d_in[19 + 6 * l];
        const float* b2 = (const float*)d_in[20 + 6 * l];
        // m = h + sum_nbr(h)
        agg_kernel<<<N_NODES / 2, 192, 0, stream>>>(h, row_ptr, csr, buf, N_NODES);
        // t = m @ W1 + b1 (in-place on buf; rows staged to LDS first), fused stats(t)
        hipMemsetAsync(statsT, 0, 2 * HDIM * 4, stream);
        mm_kernel<HDIM, false, false, false, true><<<N_NODES / 8, 192, 0, stream>>>(buf, W1, b1, nullptr, buf, statsT, N_NODES);
        finalize_bn_kernel<<<1, HDIM, 0, stream>>>(statsT, bw, bb, acT, HDIM, 1.0f / N_NODES);
        // h = relu( relu(BN(t)) @ W2 + b2 )
        mm_kernel<HDIM, true, true, true, false><<<N_NODES / 8, 192, 0, stream>>>(buf, W2, b2, acT, h, nullptr, N_NODES);
    }

    // global add pool
    hipMemsetAsync(g, 0, (size_t)N_GRAPHS * HDIM * 4, stream);
    pool_kernel<<<(N_NODES * HDIM) / 256, 256, 0, stream>>>(h, batch, g, N_NODES);

    // g1 = relu(BN_fc(g) @ Wl + bl), fused stats(g1)
    hipMemsetAsync(statsG, 0, 2 * HDIM * 4, stream);
    colstats_kernel<HDIM><<<64, 2 * HDIM, 0, stream>>>(g, statsG, N_GRAPHS);
    finalize_bn_kernel<<<1, HDIM, 0, stream>>>(statsG, bn_fc_w, bn_fc_b, acG, HDIM, 1.0f / N_GRAPHS);
    hipMemsetAsync(statsG1, 0, 2 * HDIM * 4, stream);
    mm_kernel<HDIM, true, false, true, true><<<N_GRAPHS / 8, 192, 0, stream>>>(g, Wl, bl, acG, g1, statsG1, N_GRAPHS);
    finalize_bn_kernel<<<1, HDIM, 0, stream>>>(statsG1, bn_hid_w, bn_hid_b, acHid, HDIM, 1.0f / N_GRAPHS);

    // logits + log_softmax
    head_kernel<<<2, 256, 0, stream>>>(g1, acHid, Wc, bc, out, N_GRAPHS);
}

// Round 2
// 854.533 us; speedup vs baseline: 1.5587x; 1.5587x over previous
//
#include <hip/hip_runtime.h>

#define N_NODES 50000
#define N_EDGES 800000
#define N_GRAPHS 512
#define F_IN 128
#define HDIM 96
#define NCLS 10
#define BN_EPS 1e-5f

// ---------------- column stats (sum, sumsq) over rows ----------------
template<int NC>
__global__ __launch_bounds__(2*NC) void colstats_kernel(const float* __restrict__ in,
                                                        float* __restrict__ stats,
                                                        int nrows) {
    const int col  = threadIdx.x % NC;
    const int half = threadIdx.x / NC;
    float s = 0.f, ss = 0.f;
    for (int r = blockIdx.x * 2 + half; r < nrows; r += gridDim.x * 2) {
        float v = in[(size_t)r * NC + col];
        s += v; ss += v * v;
    }
    __shared__ float shs[2][NC], shq[2][NC];
    shs[half][col] = s; shq[half][col] = ss;
    __syncthreads();
    if (half == 0) {
        atomicAdd(&stats[col],      s  + shs[1][col]);
        atomicAdd(&stats[NC + col], ss + shq[1][col]);
    }
}

// stats -> per-column affine (a = w*rsqrt(var+eps), c = b - mu*a)
__global__ void finalize_bn_kernel(const float* __restrict__ stats,
                                   const float* __restrict__ w,
                                   const float* __restrict__ b,
                                   float* __restrict__ ac, int ncols, float inv_n) {
    int k = blockIdx.x * blockDim.x + threadIdx.x;
    if (k < ncols) {
        float mu  = stats[k] * inv_n;
        float var = stats[ncols + k] * inv_n - mu * mu;
        float a   = w[k] * rsqrtf(var + BN_EPS);
        ac[k]         = a;
        ac[ncols + k] = b[k] - mu * a;
    }
}

// ---------------- CSR build (by dst) ----------------
__global__ void hist_kernel(const int* __restrict__ dst, int* __restrict__ deg, int ne) {
    int e = blockIdx.x * blockDim.x + threadIdx.x;
    if (e < ne) atomicAdd(&deg[dst[e]], 1);
}

__global__ __launch_bounds__(1024) void scan_kernel(const int* __restrict__ deg,
                                                    int* __restrict__ row_ptr,
                                                    int* __restrict__ cursor, int n) {
    __shared__ int sh[1024];
    const int tid = threadIdx.x;
    const int chunk = (n + 1023) / 1024;
    const int lo = tid * chunk;
    const int hi = min(lo + chunk, n);
    int s = 0;
    for (int i = lo; i < hi; i++) s += deg[i];
    sh[tid] = s;
    __syncthreads();
    for (int off = 1; off < 1024; off <<= 1) {
        int v = 0;
        if (tid >= off) v = sh[tid - off];
        __syncthreads();
        if (tid >= off) sh[tid] += v;
        __syncthreads();
    }
    int run = (tid == 0) ? 0 : sh[tid - 1];
    for (int i = lo; i < hi; i++) {
        row_ptr[i] = run; cursor[i] = run;
        run += deg[i];
    }
    if (tid == 1023) row_ptr[n] = sh[1023];
}

__global__ void fill_kernel(const int* __restrict__ src, const int* __restrict__ dst,
                            int* __restrict__ cursor, int* __restrict__ csr_src, int ne) {
    int e = blockIdx.x * blockDim.x + threadIdx.x;
    if (e < ne) {
        int pos = atomicAdd(&cursor[dst[e]], 1);
        csr_src[pos] = src[e];
    }
}

// ---------------- GIN aggregation: m[n] = h[n] + sum_{s in nbr(n)} h[s] ----------------
__global__ __launch_bounds__(192) void agg_kernel(const float* __restrict__ h,
                                                  const int* __restrict__ row_ptr,
                                                  const int* __restrict__ csr_src,
                                                  float* __restrict__ m, int n) {
    const int j    = threadIdx.x % HDIM;
    const int node = blockIdx.x * 2 + threadIdx.x / HDIM;
    if (node >= n) return;
    const int p0 = row_ptr[node], p1 = row_ptr[node + 1];
    float acc = h[(size_t)node * HDIM + j];
    for (int p = p0; p < p1; p++) {
        int s = csr_src[p];
        acc += h[(size_t)s * HDIM + j];
    }
    m[(size_t)node * HDIM + j] = acc;
}

// ---------------- weight-resident tiled matmul ----------------
// out[nrows][96] = [opt OUT_RELU]( [opt IN_RELU][opt BN-affine](in[nrows][KDIM]) @ W + bias )
// optional fused column-stats of the output. Block: 192 threads, 4x4 register tile,
// 32-row chunks, grid-stride so W is staged once per block.
template<int KDIM, bool IN_AFF, bool IN_RELU, bool OUT_RELU, bool STATS>
__global__ __launch_bounds__(192) void mm_kernel(const float* __restrict__ in,
                                                 const float* __restrict__ W,
                                                 const float* __restrict__ bias,
                                                 const float* __restrict__ ac,
                                                 float* __restrict__ out,
                                                 float* __restrict__ stats, int nrows) {
    constexpr int KG = KDIM / 4;
    __shared__ float ws[KDIM][96];
    __shared__ float xs[32][KDIM];   // columns stored XOR-swizzled: [r][4*((k/4)^(r&7)) + k%4]
    const int tid = threadIdx.x;
    const int cg  = tid % 24;        // cols 4cg .. 4cg+3
    const int rg  = tid / 24;        // rows rg, rg+8, rg+16, rg+24 within chunk

    for (int i = tid; i < KDIM * 24; i += 192) {
        int k = i / 24, c4 = i % 24;
        *(float4*)&ws[k][c4 * 4] = *(const float4*)&W[(size_t)k * 96 + c4 * 4];
    }
    const float4 bj = *(const float4*)&bias[cg * 4];

    float s0=0,s1=0,s2=0,s3=0, q0=0,q1=0,q2=0,q3=0;

    const int nchunks = (nrows + 31) / 32;
    for (int chunk = blockIdx.x; chunk < nchunks; chunk += gridDim.x) {
        const int row0 = chunk * 32;
        __syncthreads();   // previous chunk's xs reads complete (also covers ws staging)
        for (int i = tid; i < 32 * KG; i += 192) {
            int r = i / KG, g = i % KG;
            int gr = row0 + r;
            float4 v = make_float4(0.f, 0.f, 0.f, 0.f);
            if (gr < nrows) v = *(const float4*)&in[(size_t)gr * KDIM + g * 4];
            if constexpr (IN_AFF) {
                float4 a = *(const float4*)&ac[g * 4];
                float4 c = *(const float4*)&ac[KDIM + g * 4];
                v.x = v.x * a.x + c.x; v.y = v.y * a.y + c.y;
                v.z = v.z * a.z + c.z; v.w = v.w * a.w + c.w;
            }
            if constexpr (IN_RELU) {
                v.x = fmaxf(v.x, 0.f); v.y = fmaxf(v.y, 0.f);
                v.z = fmaxf(v.z, 0.f); v.w = fmaxf(v.w, 0.f);
            }
            *(float4*)&xs[r][4 * (g ^ (r & 7))] = v;
        }
        __syncthreads();

        float acc[4][4];
        #pragma unroll
        for (int m = 0; m < 4; m++) {
            acc[m][0] = bj.x; acc[m][1] = bj.y; acc[m][2] = bj.z; acc[m][3] = bj.w;
        }

        #pragma unroll 4
        for (int g = 0; g < KG; g++) {
            const int xi = 4 * (g ^ rg);
            float4 xv0 = *(const float4*)&xs[rg     ][xi];
            float4 xv1 = *(const float4*)&xs[rg +  8][xi];
            float4 xv2 = *(const float4*)&xs[rg + 16][xi];
            float4 xv3 = *(const float4*)&xs[rg + 24][xi];
            #pragma unroll
            for (int i = 0; i < 4; i++) {
                float4 wv = *(const float4*)&ws[g * 4 + i][cg * 4];
                float x0 = (i==0)?xv0.x:(i==1)?xv0.y:(i==2)?xv0.z:xv0.w;
                float x1 = (i==0)?xv1.x:(i==1)?xv1.y:(i==2)?xv1.z:xv1.w;
                float x2 = (i==0)?xv2.x:(i==1)?xv2.y:(i==2)?xv2.z:xv2.w;
                float x3 = (i==0)?xv3.x:(i==1)?xv3.y:(i==2)?xv3.z:xv3.w;
                acc[0][0] = fmaf(x0, wv.x, acc[0][0]); acc[0][1] = fmaf(x0, wv.y, acc[0][1]);
                acc[0][2] = fmaf(x0, wv.z, acc[0][2]); acc[0][3] = fmaf(x0, wv.w, acc[0][3]);
                acc[1][0] = fmaf(x1, wv.x, acc[1][0]); acc[1][1] = fmaf(x1, wv.y, acc[1][1]);
                acc[1][2] = fmaf(x1, wv.z, acc[1][2]); acc[1][3] = fmaf(x1, wv.w, acc[1][3]);
                acc[2][0] = fmaf(x2, wv.x, acc[2][0]); acc[2][1] = fmaf(x2, wv.y, acc[2][1]);
                acc[2][2] = fmaf(x2, wv.z, acc[2][2]); acc[2][3] = fmaf(x2, wv.w, acc[2][3]);
                acc[3][0] = fmaf(x3, wv.x, acc[3][0]); acc[3][1] = fmaf(x3, wv.y, acc[3][1]);
                acc[3][2] = fmaf(x3, wv.z, acc[3][2]); acc[3][3] = fmaf(x3, wv.w, acc[3][3]);
            }
        }

        #pragma unroll
        for (int m = 0; m < 4; m++) {
            const int gr = row0 + rg + 8 * m;
            if (gr < nrows) {
                float4 o = make_float4(acc[m][0], acc[m][1], acc[m][2], acc[m][3]);
                if constexpr (OUT_RELU) {
                    o.x = fmaxf(o.x, 0.f); o.y = fmaxf(o.y, 0.f);
                    o.z = fmaxf(o.z, 0.f); o.w = fmaxf(o.w, 0.f);
                }
                *(float4*)&out[(size_t)gr * 96 + cg * 4] = o;
                if constexpr (STATS) {
                    s0 += o.x; q0 += o.x * o.x;
                    s1 += o.y; q1 += o.y * o.y;
                    s2 += o.z; q2 += o.z * o.z;
                    s3 += o.w; q3 += o.w * o.w;
                }
            }
        }
    }

    if constexpr (STATS) {
        __syncthreads();
        float* rs = &xs[0][0];        // overlay: [8][96] sums
        float* rq = rs + 8 * 96;      // [8][96] sumsq
        rs[rg * 96 + cg * 4 + 0] = s0; rs[rg * 96 + cg * 4 + 1] = s1;
        rs[rg * 96 + cg * 4 + 2] = s2; rs[rg * 96 + cg * 4 + 3] = s3;
        rq[rg * 96 + cg * 4 + 0] = q0; rq[rg * 96 + cg * 4 + 1] = q1;
        rq[rg * 96 + cg * 4 + 2] = q2; rq[rg * 96 + cg * 4 + 3] = q3;
        __syncthreads();
        if (tid < 96) {
            float a = 0.f, b = 0.f;
            #pragma unroll
            for (int r = 0; r < 8; r++) { a += rs[r * 96 + tid]; b += rq[r * 96 + tid]; }
            atomicAdd(&stats[tid],      a);
            atomicAdd(&stats[96 + tid], b);
        }
    }
}

// ---------------- global add pool ----------------
__global__ void pool_kernel(const float* __restrict__ h, const int* __restrict__ batch,
                            float* __restrict__ g, int n) {
    int idx = blockIdx.x * blockDim.x + threadIdx.x;
    if (idx < n * HDIM) {
        int node = idx / HDIM, j = idx % HDIM;
        atomicAdd(&g[(size_t)batch[node] * HDIM + j], h[idx]);
    }
}

// ---------------- head: logits = BN(g1) @ Wc + bc, then log_softmax ----------------
__global__ void head_kernel(const float* __restrict__ g1, const float* __restrict__ ac,
                            const float* __restrict__ Wc, const float* __restrict__ bc,
                            float* __restrict__ out, int ngraphs) {
    int gi = blockIdx.x * blockDim.x + threadIdx.x;
    if (gi >= ngraphs) return;
    float v[NCLS];
    #pragma unroll
    for (int c = 0; c < NCLS; c++) v[c] = bc[c];
    for (int k = 0; k < HDIM; k++) {
        float x = g1[(size_t)gi * HDIM + k] * ac[k] + ac[HDIM + k];
        #pragma unroll
        for (int c = 0; c < NCLS; c++) v[c] = fmaf(x, Wc[k * NCLS + c], v[c]);
    }
    float mx = v[0];
    #pragma unroll
    for (int c = 1; c < NCLS; c++) mx = fmaxf(mx, v[c]);
    float sum = 0.f;
    #pragma unroll
    for (int c = 0; c < NCLS; c++) sum += expf(v[c] - mx);
    float lse = mx + logf(sum);
    #pragma unroll
    for (int c = 0; c < NCLS; c++) out[(size_t)gi * NCLS + c] = v[c] - lse;
}

extern "C" void kernel_launch(void* const* d_in, const int* in_sizes, int n_in,
                              void* d_out, int out_size, void* d_ws, size_t ws_size,
                              hipStream_t stream) {
    const float* x         = (const float*)d_in[0];
    const int*   ei        = (const int*)  d_in[1];
    const int*   batch     = (const int*)  d_in[2];
    const float* bn_feat_w = (const float*)d_in[3];
    const float* bn_feat_b = (const float*)d_in[4];
    const float* Wf        = (const float*)d_in[5];
    const float* bfv       = (const float*)d_in[6];
    const float* bn_fc_w   = (const float*)d_in[7];
    const float* bn_fc_b   = (const float*)d_in[8];
    const float* Wl        = (const float*)d_in[9];
    const float* bl        = (const float*)d_in[10];
    const float* bn_hid_w  = (const float*)d_in[11];
    const float* bn_hid_b  = (const float*)d_in[12];
    const float* Wc        = (const float*)d_in[13];
    const float* bc        = (const float*)d_in[14];
    float* out = (float*)d_out;

    char* p = (char*)d_ws;
    auto alloc = [&](size_t bytes) { char* q = p; p += (bytes + 255) & ~(size_t)255; return q; };
    float* h      = (float*)alloc((size_t)N_NODES * HDIM * 4);
    float* buf    = (float*)alloc((size_t)N_NODES * HDIM * 4);
    float* g      = (float*)alloc((size_t)N_GRAPHS * HDIM * 4);
    float* g1     = (float*)alloc((size_t)N_GRAPHS * HDIM * 4);
    float* statsX = (float*)alloc(2 * F_IN * 4);
    float* acX    = (float*)alloc(2 * F_IN * 4);
    float* statsT = (float*)alloc(2 * HDIM * 4);
    float* acT    = (float*)alloc(2 * HDIM * 4);
    float* statsG = (float*)alloc(2 * HDIM * 4);
    float* acG    = (float*)alloc(2 * HDIM * 4);
    float* statsG1= (float*)alloc(2 * HDIM * 4);
    float* acHid  = (float*)alloc(2 * HDIM * 4);
    int* deg      = (int*)alloc((size_t)N_NODES * 4);
    int* row_ptr  = (int*)alloc((size_t)(N_NODES + 1) * 4);
    int* cursor   = (int*)alloc((size_t)N_NODES * 4);
    int* csr      = (int*)alloc((size_t)N_EDGES * 4);

    const int* srcp = ei;
    const int* dstp = ei + N_EDGES;

    const int nchunks = (N_NODES + 31) / 32;
    const int grid128 = (nchunks < 512) ? nchunks : 512;  // K=128: 64KB LDS -> 2 blk/CU
    const int grid96  = (nchunks < 750) ? nchunks : 750;  // K=96:  48KB LDS -> 3 blk/CU
    const int gridG   = (N_GRAPHS + 31) / 32;

    // BN(x) stats, then h = relu(BN(x) @ Wf + bf)
    hipMemsetAsync(statsX, 0, 2 * F_IN * 4, stream);
    colstats_kernel<F_IN><<<256, 2 * F_IN, 0, stream>>>(x, statsX, N_NODES);
    finalize_bn_kernel<<<1, F_IN, 0, stream>>>(statsX, bn_feat_w, bn_feat_b, acX, F_IN, 1.0f / N_NODES);
    mm_kernel<F_IN, true, false, true, false><<<grid128, 192, 0, stream>>>(x, Wf, bfv, acX, h, nullptr, N_NODES);

    // CSR build (once; reused by all 3 layers)
    hipMemsetAsync(deg, 0, (size_t)N_NODES * 4, stream);
    hist_kernel<<<(N_EDGES + 255) / 256, 256, 0, stream>>>(dstp, deg, N_EDGES);
    scan_kernel<<<1, 1024, 0, stream>>>(deg, row_ptr, cursor, N_NODES);
    fill_kernel<<<(N_EDGES + 255) / 256, 256, 0, stream>>>(srcp, dstp, cursor, csr, N_EDGES);

    for (int l = 0; l < 3; l++) {
        const float* W1 = (const float*)d_in[15 + 6 * l];
        const float* b1 = (const float*)d_in[16 + 6 * l];
        const float* bw = (const float*)d_in[17 + 6 * l];
        const float* bb = (const float*)d_in[18 + 6 * l];
        const float* W2 = (const float*)d_in[19 + 6 * l];
        const float* b2 = (const float*)d_in[20 + 6 * l];
        // m = h + sum_nbr(h)
        agg_kernel<<<N_NODES / 2, 192, 0, stream>>>(h, row_ptr, csr, buf, N_NODES);
        // t = m @ W1 + b1 (in-place on buf), fused stats(t)
        hipMemsetAsync(statsT, 0, 2 * HDIM * 4, stream);
        mm_kernel<HDIM, false, false, false, true><<<grid96, 192, 0, stream>>>(buf, W1, b1, nullptr, buf, statsT, N_NODES);
        finalize_bn_kernel<<<1, HDIM, 0, stream>>>(statsT, bw, bb, acT, HDIM, 1.0f / N_NODES);
        // h = relu( relu(BN(t)) @ W2 + b2 )
        mm_kernel<HDIM, true, true, true, false><<<grid96, 192, 0, stream>>>(buf, W2, b2, acT, h, nullptr, N_NODES);
    }

    // global add pool
    hipMemsetAsync(g, 0, (size_t)N_GRAPHS * HDIM * 4, stream);
    pool_kernel<<<(N_NODES * HDIM) / 256, 256, 0, stream>>>(h, batch, g, N_NODES);

    // g1 = relu(BN_fc(g) @ Wl + bl), fused stats(g1)
    hipMemsetAsync(statsG, 0, 2 * HDIM * 4, stream);
    colstats_kernel<HDIM><<<64, 2 * HDIM, 0, stream>>>(g, statsG, N_GRAPHS);
    finalize_bn_kernel<<<1, HDIM, 0, stream>>>(statsG, bn_fc_w, bn_fc_b, acG, HDIM, 1.0f / N_GRAPHS);
    hipMemsetAsync(statsG1, 0, 2 * HDIM * 4, stream);
    mm_kernel<HDIM, true, false, true, true><<<gridG, 192, 0, stream>>>(g, Wl, bl, acG, g1, statsG1, N_GRAPHS);
    finalize_bn_kernel<<<1, HDIM, 0, stream>>>(statsG1, bn_hid_w, bn_hid_b, acHid, HDIM, 1.0f / N_GRAPHS);

    // logits + log_softmax
    head_kernel<<<2, 256, 0, stream>>>(g1, acHid, Wc, bc, out, N_GRAPHS);
}

// Round 3
// 539.292 us; speedup vs baseline: 2.4698x; 1.5845x over previous
//
#include <hip/hip_runtime.h>

#define N_NODES 50000
#define N_EDGES 800000
#define N_GRAPHS 512
#define F_IN 128
#define HDIM 96
#define NCLS 10
#define BN_EPS 1e-5f

typedef unsigned int u32;
typedef unsigned short u16;

__device__ __forceinline__ u16 f2bf(float f) {
    u32 u = __float_as_uint(f);
    u32 r = (u + 0x7fffu + ((u >> 16) & 1u)) >> 16;   // RNE
    return (u16)r;
}
__device__ __forceinline__ float bflo(u32 w) { return __uint_as_float(w << 16); }
__device__ __forceinline__ float bfhi(u32 w) { return __uint_as_float(w & 0xffff0000u); }

// ---------------- column stats (sum, sumsq) over rows ----------------
template<int NC>
__global__ __launch_bounds__(2*NC) void colstats_kernel(const float* __restrict__ in,
                                                        float* __restrict__ stats,
                                                        int nrows) {
    const int col  = threadIdx.x % NC;
    const int half = threadIdx.x / NC;
    float s = 0.f, ss = 0.f;
    for (int r = blockIdx.x * 2 + half; r < nrows; r += gridDim.x * 2) {
        float v = in[(size_t)r * NC + col];
        s += v; ss += v * v;
    }
    __shared__ float shs[2][NC], shq[2][NC];
    shs[half][col] = s; shq[half][col] = ss;
    __syncthreads();
    if (half == 0) {
        atomicAdd(&stats[col],      s  + shs[1][col]);
        atomicAdd(&stats[NC + col], ss + shq[1][col]);
    }
}

// stats -> per-column affine (a = w*rsqrt(var+eps), c = b - mu*a)
__global__ void finalize_bn_kernel(const float* __restrict__ stats,
                                   const float* __restrict__ w,
                                   const float* __restrict__ b,
                                   float* __restrict__ ac, int ncols, float inv_n) {
    int k = blockIdx.x * blockDim.x + threadIdx.x;
    if (k < ncols) {
        float mu  = stats[k] * inv_n;
        float var = stats[ncols + k] * inv_n - mu * mu;
        float a   = w[k] * rsqrtf(var + BN_EPS);
        ac[k]         = a;
        ac[ncols + k] = b[k] - mu * a;
    }
}

// ---------------- CSR build (by dst) ----------------
__global__ void hist_kernel(const int* __restrict__ dst, int* __restrict__ deg, int ne) {
    int e = blockIdx.x * blockDim.x + threadIdx.x;
    if (e < ne) atomicAdd(&deg[dst[e]], 1);
}

// multi-block exclusive scan: phase 1 — per-block LDS scan, write local-exclusive + block total
__global__ __launch_bounds__(1024) void scan1_kernel(const int* __restrict__ deg,
                                                     int* __restrict__ tmp,
                                                     int* __restrict__ partial, int n) {
    __shared__ int sh[1024];
    const int i = blockIdx.x * 1024 + threadIdx.x;
    const int d = (i < n) ? deg[i] : 0;
    sh[threadIdx.x] = d;
    __syncthreads();
    for (int off = 1; off < 1024; off <<= 1) {
        int v = 0;
        if (threadIdx.x >= off) v = sh[threadIdx.x - off];
        __syncthreads();
        sh[threadIdx.x] += v;
        __syncthreads();
    }
    if (i < n) tmp[i] = sh[threadIdx.x] - d;       // exclusive within block
    if (threadIdx.x == 1023) partial[blockIdx.x] = sh[1023];
}

// phase 2 — one wave exclusive-scans the block totals (nparts <= 64)
__global__ void scan2_kernel(int* __restrict__ partial, int nparts) {
    const int t = threadIdx.x;
    int d = (t < nparts) ? partial[t] : 0;
    int v = d;
    for (int off = 1; off < 64; off <<= 1) {
        int u = __shfl_up(v, off, 64);
        if (t >= off) v += u;
    }
    if (t < nparts) partial[t] = v - d;
}

// phase 3 — add block offset, emit row_ptr + cursor
__global__ __launch_bounds__(1024) void scan3_kernel(const int* __restrict__ tmp,
                                                     const int* __restrict__ partial,
                                                     const int* __restrict__ deg,
                                                     int* __restrict__ row_ptr,
                                                     int* __restrict__ cursor, int n) {
    const int i = blockIdx.x * 1024 + threadIdx.x;
    if (i < n) {
        int v = tmp[i] + partial[blockIdx.x];
        row_ptr[i] = v; cursor[i] = v;
        if (i == n - 1) row_ptr[n] = v + deg[i];
    }
}

__global__ void fill_kernel(const int* __restrict__ src, const int* __restrict__ dst,
                            int* __restrict__ cursor, int* __restrict__ csr_src, int ne) {
    int e = blockIdx.x * blockDim.x + threadIdx.x;
    if (e < ne) {
        int pos = atomicAdd(&cursor[dst[e]], 1);
        csr_src[pos] = src[e];
    }
}

// ---------------- GIN aggregation: m[n] = h[n] + sum_{s in nbr(n)} h[s] ----------------
// h stored as bf16 (halves gather bytes); 24 threads/node, uint2 loads (4 bf16/lane),
// edge loop unrolled x4 so 4 gathers are in flight.
__global__ __launch_bounds__(192) void agg_kernel(const u16* __restrict__ hb,
                                                  const int* __restrict__ row_ptr,
                                                  const int* __restrict__ csr,
                                                  float* __restrict__ m, int n) {
    const int jj   = threadIdx.x % 24;       // columns jj*4 .. jj*4+3
    const int node = blockIdx.x * 8 + threadIdx.x / 24;
    if (node >= n) return;
    const int p0 = row_ptr[node], p1 = row_ptr[node + 1];
    uint2 sv = *(const uint2*)&hb[(size_t)node * 96 + jj * 4];
    float a0 = bflo(sv.x), a1 = bfhi(sv.x), a2 = bflo(sv.y), a3 = bfhi(sv.y);
    int p = p0;
    for (; p + 4 <= p1; p += 4) {
        int s0 = csr[p], s1 = csr[p + 1], s2 = csr[p + 2], s3 = csr[p + 3];
        uint2 v0 = *(const uint2*)&hb[(size_t)s0 * 96 + jj * 4];
        uint2 v1 = *(const uint2*)&hb[(size_t)s1 * 96 + jj * 4];
        uint2 v2 = *(const uint2*)&hb[(size_t)s2 * 96 + jj * 4];
        uint2 v3 = *(const uint2*)&hb[(size_t)s3 * 96 + jj * 4];
        a0 += (bflo(v0.x) + bflo(v1.x)) + (bflo(v2.x) + bflo(v3.x));
        a1 += (bfhi(v0.x) + bfhi(v1.x)) + (bfhi(v2.x) + bfhi(v3.x));
        a2 += (bflo(v0.y) + bflo(v1.y)) + (bflo(v2.y) + bflo(v3.y));
        a3 += (bfhi(v0.y) + bfhi(v1.y)) + (bfhi(v2.y) + bfhi(v3.y));
    }
    for (; p < p1; p++) {
        int s = csr[p];
        uint2 v = *(const uint2*)&hb[(size_t)s * 96 + jj * 4];
        a0 += bflo(v.x); a1 += bfhi(v.x); a2 += bflo(v.y); a3 += bfhi(v.y);
    }
    *(float4*)&m[(size_t)node * 96 + jj * 4] = make_float4(a0, a1, a2, a3);
}

// ---------------- weight-resident tiled matmul ----------------
template<int KDIM, bool IN_AFF, bool IN_RELU, bool OUT_RELU, bool STATS, bool OUT_BF16>
__global__ __launch_bounds__(192) void mm_kernel(const float* __restrict__ in,
                                                 const float* __restrict__ W,
                                                 const float* __restrict__ bias,
                                                 const float* __restrict__ ac,
                                                 void* __restrict__ out_,
                                                 float* __restrict__ stats, int nrows) {
    constexpr int KG = KDIM / 4;
    __shared__ float ws[KDIM][96];
    __shared__ float xs[32][KDIM];   // columns stored XOR-swizzled: [r][4*((k/4)^(r&7)) + k%4]
    const int tid = threadIdx.x;
    const int cg  = tid % 24;        // cols 4cg .. 4cg+3
    const int rg  = tid / 24;        // rows rg, rg+8, rg+16, rg+24 within chunk

    for (int i = tid; i < KDIM * 24; i += 192) {
        int k = i / 24, c4 = i % 24;
        *(float4*)&ws[k][c4 * 4] = *(const float4*)&W[(size_t)k * 96 + c4 * 4];
    }
    const float4 bj = *(const float4*)&bias[cg * 4];

    float s0=0,s1=0,s2=0,s3=0, q0=0,q1=0,q2=0,q3=0;

    const int nchunks = (nrows + 31) / 32;
    for (int chunk = blockIdx.x; chunk < nchunks; chunk += gridDim.x) {
        const int row0 = chunk * 32;
        __syncthreads();   // previous chunk's xs reads complete (also covers ws staging)
        for (int i = tid; i < 32 * KG; i += 192) {
            int r = i / KG, g = i % KG;
            int gr = row0 + r;
            float4 v = make_float4(0.f, 0.f, 0.f, 0.f);
            if (gr < nrows) v = *(const float4*)&in[(size_t)gr * KDIM + g * 4];
            if constexpr (IN_AFF) {
                float4 a = *(const float4*)&ac[g * 4];
                float4 c = *(const float4*)&ac[KDIM + g * 4];
                v.x = v.x * a.x + c.x; v.y = v.y * a.y + c.y;
                v.z = v.z * a.z + c.z; v.w = v.w * a.w + c.w;
            }
            if constexpr (IN_RELU) {
                v.x = fmaxf(v.x, 0.f); v.y = fmaxf(v.y, 0.f);
                v.z = fmaxf(v.z, 0.f); v.w = fmaxf(v.w, 0.f);
            }
            *(float4*)&xs[r][4 * (g ^ (r & 7))] = v;
        }
        __syncthreads();

        float acc[4][4];
        #pragma unroll
        for (int m = 0; m < 4; m++) {
            acc[m][0] = bj.x; acc[m][1] = bj.y; acc[m][2] = bj.z; acc[m][3] = bj.w;
        }

        #pragma unroll 4
        for (int g = 0; g < KG; g++) {
            const int xi = 4 * (g ^ rg);
            float4 xv0 = *(const float4*)&xs[rg     ][xi];
            float4 xv1 = *(const float4*)&xs[rg +  8][xi];
            float4 xv2 = *(const float4*)&xs[rg + 16][xi];
            float4 xv3 = *(const float4*)&xs[rg + 24][xi];
            #pragma unroll
            for (int i = 0; i < 4; i++) {
                float4 wv = *(const float4*)&ws[g * 4 + i][cg * 4];
                float x0 = (i==0)?xv0.x:(i==1)?xv0.y:(i==2)?xv0.z:xv0.w;
                float x1 = (i==0)?xv1.x:(i==1)?xv1.y:(i==2)?xv1.z:xv1.w;
                float x2 = (i==0)?xv2.x:(i==1)?xv2.y:(i==2)?xv2.z:xv2.w;
                float x3 = (i==0)?xv3.x:(i==1)?xv3.y:(i==2)?xv3.z:xv3.w;
                acc[0][0] = fmaf(x0, wv.x, acc[0][0]); acc[0][1] = fmaf(x0, wv.y, acc[0][1]);
                acc[0][2] = fmaf(x0, wv.z, acc[0][2]); acc[0][3] = fmaf(x0, wv.w, acc[0][3]);
                acc[1][0] = fmaf(x1, wv.x, acc[1][0]); acc[1][1] = fmaf(x1, wv.y, acc[1][1]);
                acc[1][2] = fmaf(x1, wv.z, acc[1][2]); acc[1][3] = fmaf(x1, wv.w, acc[1][3]);
                acc[2][0] = fmaf(x2, wv.x, acc[2][0]); acc[2][1] = fmaf(x2, wv.y, acc[2][1]);
                acc[2][2] = fmaf(x2, wv.z, acc[2][2]); acc[2][3] = fmaf(x2, wv.w, acc[2][3]);
                acc[3][0] = fmaf(x3, wv.x, acc[3][0]); acc[3][1] = fmaf(x3, wv.y, acc[3][1]);
                acc[3][2] = fmaf(x3, wv.z, acc[3][2]); acc[3][3] = fmaf(x3, wv.w, acc[3][3]);
            }
        }

        #pragma unroll
        for (int m = 0; m < 4; m++) {
            const int gr = row0 + rg + 8 * m;
            if (gr < nrows) {
                float4 o = make_float4(acc[m][0], acc[m][1], acc[m][2], acc[m][3]);
                if constexpr (OUT_RELU) {
                    o.x = fmaxf(o.x, 0.f); o.y = fmaxf(o.y, 0.f);
                    o.z = fmaxf(o.z, 0.f); o.w = fmaxf(o.w, 0.f);
                }
                if constexpr (OUT_BF16) {
                    u16* ob = (u16*)out_;
                    ushort4 t;
                    t.x = f2bf(o.x); t.y = f2bf(o.y); t.z = f2bf(o.z); t.w = f2bf(o.w);
                    *(ushort4*)&ob[(size_t)gr * 96 + cg * 4] = t;
                } else {
                    float* of = (float*)out_;
                    *(float4*)&of[(size_t)gr * 96 + cg * 4] = o;
                }
                if constexpr (STATS) {
                    s0 += o.x; q0 += o.x * o.x;
                    s1 += o.y; q1 += o.y * o.y;
                    s2 += o.z; q2 += o.z * o.z;
                    s3 += o.w; q3 += o.w * o.w;
                }
            }
        }
    }

    if constexpr (STATS) {
        __syncthreads();
        float* rs = &xs[0][0];        // overlay: [8][96] sums
        float* rq = rs + 8 * 96;      // [8][96] sumsq
        rs[rg * 96 + cg * 4 + 0] = s0; rs[rg * 96 + cg * 4 + 1] = s1;
        rs[rg * 96 + cg * 4 + 2] = s2; rs[rg * 96 + cg * 4 + 3] = s3;
        rq[rg * 96 + cg * 4 + 0] = q0; rq[rg * 96 + cg * 4 + 1] = q1;
        rq[rg * 96 + cg * 4 + 2] = q2; rq[rg * 96 + cg * 4 + 3] = q3;
        __syncthreads();
        if (tid < 96) {
            float a = 0.f, b = 0.f;
            #pragma unroll
            for (int r = 0; r < 8; r++) { a += rs[r * 96 + tid]; b += rq[r * 96 + tid]; }
            atomicAdd(&stats[tid],      a);
            atomicAdd(&stats[96 + tid], b);
        }
    }
}

// ---------------- global add pool (bf16 input) ----------------
__global__ void pool_kernel(const u16* __restrict__ hb, const int* __restrict__ batch,
                            float* __restrict__ g, int n) {
    int idx = blockIdx.x * blockDim.x + threadIdx.x;
    if (idx < n * 48) {
        int node = idx / 48, jp = idx % 48;
        u32 v = *(const u32*)&hb[(size_t)node * 96 + jp * 2];
        int b = batch[node];
        atomicAdd(&g[(size_t)b * 96 + jp * 2],     bflo(v));
        atomicAdd(&g[(size_t)b * 96 + jp * 2 + 1], bfhi(v));
    }
}

// ---------------- head: logits = BN(g1) @ Wc + bc, then log_softmax ----------------
__global__ void head_kernel(const float* __restrict__ g1, const float* __restrict__ ac,
                            const float* __restrict__ Wc, const float* __restrict__ bc,
                            float* __restrict__ out, int ngraphs) {
    int gi = blockIdx.x * blockDim.x + threadIdx.x;
    if (gi >= ngraphs) return;
    float v[NCLS];
    #pragma unroll
    for (int c = 0; c < NCLS; c++) v[c] = bc[c];
    for (int k = 0; k < HDIM; k++) {
        float x = g1[(size_t)gi * HDIM + k] * ac[k] + ac[HDIM + k];
        #pragma unroll
        for (int c = 0; c < NCLS; c++) v[c] = fmaf(x, Wc[k * NCLS + c], v[c]);
    }
    float mx = v[0];
    #pragma unroll
    for (int c = 1; c < NCLS; c++) mx = fmaxf(mx, v[c]);
    float sum = 0.f;
    #pragma unroll
    for (int c = 0; c < NCLS; c++) sum += expf(v[c] - mx);
    float lse = mx + logf(sum);
    #pragma unroll
    for (int c = 0; c < NCLS; c++) out[(size_t)gi * NCLS + c] = v[c] - lse;
}

extern "C" void kernel_launch(void* const* d_in, const int* in_sizes, int n_in,
                              void* d_out, int out_size, void* d_ws, size_t ws_size,
                              hipStream_t stream) {
    const float* x         = (const float*)d_in[0];
    const int*   ei        = (const int*)  d_in[1];
    const int*   batch     = (const int*)  d_in[2];
    const float* bn_feat_w = (const float*)d_in[3];
    const float* bn_feat_b = (const float*)d_in[4];
    const float* Wf        = (const float*)d_in[5];
    const float* bfv       = (const float*)d_in[6];
    const float* bn_fc_w   = (const float*)d_in[7];
    const float* bn_fc_b   = (const float*)d_in[8];
    const float* Wl        = (const float*)d_in[9];
    const float* bl        = (const float*)d_in[10];
    const float* bn_hid_w  = (const float*)d_in[11];
    const float* bn_hid_b  = (const float*)d_in[12];
    const float* Wc        = (const float*)d_in[13];
    const float* bc        = (const float*)d_in[14];
    float* out = (float*)d_out;

    char* p = (char*)d_ws;
    auto alloc = [&](size_t bytes) { char* q = p; p += (bytes + 255) & ~(size_t)255; return q; };
    u16*   hb     = (u16*)  alloc((size_t)N_NODES * HDIM * 2);
    float* buf    = (float*)alloc((size_t)N_NODES * HDIM * 4);
    float* g      = (float*)alloc((size_t)N_GRAPHS * HDIM * 4);
    float* g1     = (float*)alloc((size_t)N_GRAPHS * HDIM * 4);
    float* statsX = (float*)alloc(2 * F_IN * 4);
    float* acX    = (float*)alloc(2 * F_IN * 4);
    float* statsT = (float*)alloc(2 * HDIM * 4);
    float* acT    = (float*)alloc(2 * HDIM * 4);
    float* statsG = (float*)alloc(2 * HDIM * 4);
    float* acG    = (float*)alloc(2 * HDIM * 4);
    float* statsG1= (float*)alloc(2 * HDIM * 4);
    float* acHid  = (float*)alloc(2 * HDIM * 4);
    int* deg      = (int*)alloc((size_t)N_NODES * 4);
    int* row_ptr  = (int*)alloc((size_t)(N_NODES + 1) * 4);
    int* cursor   = (int*)alloc((size_t)N_NODES * 4);
    int* csr      = (int*)alloc((size_t)N_EDGES * 4);
    int* stmp     = (int*)alloc((size_t)N_NODES * 4);
    int* spart    = (int*)alloc(64 * 4);

    const int* srcp = ei;
    const int* dstp = ei + N_EDGES;

    const int nchunks = (N_NODES + 31) / 32;
    const int grid128 = (nchunks < 512) ? nchunks : 512;
    const int grid96  = (nchunks < 750) ? nchunks : 750;
    const int gridG   = (N_GRAPHS + 31) / 32;
    const int nscan   = (N_NODES + 1023) / 1024;

    // BN(x) stats, then h = relu(BN(x) @ Wf + bf)  (h stored bf16)
    hipMemsetAsync(statsX, 0, 2 * F_IN * 4, stream);
    colstats_kernel<F_IN><<<256, 2 * F_IN, 0, stream>>>(x, statsX, N_NODES);
    finalize_bn_kernel<<<1, F_IN, 0, stream>>>(statsX, bn_feat_w, bn_feat_b, acX, F_IN, 1.0f / N_NODES);
    mm_kernel<F_IN, true, false, true, false, true><<<grid128, 192, 0, stream>>>(x, Wf, bfv, acX, hb, nullptr, N_NODES);

    // CSR build (once; reused by all 3 layers)
    hipMemsetAsync(deg, 0, (size_t)N_NODES * 4, stream);
    hist_kernel<<<(N_EDGES + 255) / 256, 256, 0, stream>>>(dstp, deg, N_EDGES);
    scan1_kernel<<<nscan, 1024, 0, stream>>>(deg, stmp, spart, N_NODES);
    scan2_kernel<<<1, 64, 0, stream>>>(spart, nscan);
    scan3_kernel<<<nscan, 1024, 0, stream>>>(stmp, spart, deg, row_ptr, cursor, N_NODES);
    fill_kernel<<<(N_EDGES + 255) / 256, 256, 0, stream>>>(srcp, dstp, cursor, csr, N_EDGES);

    for (int l = 0; l < 3; l++) {
        const float* W1 = (const float*)d_in[15 + 6 * l];
        const float* b1 = (const float*)d_in[16 + 6 * l];
        const float* bw = (const float*)d_in[17 + 6 * l];
        const float* bb = (const float*)d_in[18 + 6 * l];
        const float* W2 = (const float*)d_in[19 + 6 * l];
        const float* b2 = (const float*)d_in[20 + 6 * l];
        // m = h + sum_nbr(h)  (bf16 gathers -> f32 buf)
        agg_kernel<<<(N_NODES + 7) / 8, 192, 0, stream>>>(hb, row_ptr, csr, buf, N_NODES);
        // t = m @ W1 + b1 (in-place on buf), fused stats(t)
        hipMemsetAsync(statsT, 0, 2 * HDIM * 4, stream);
        mm_kernel<HDIM, false, false, false, true, false><<<grid96, 192, 0, stream>>>(buf, W1, b1, nullptr, buf, statsT, N_NODES);
        finalize_bn_kernel<<<1, HDIM, 0, stream>>>(statsT, bw, bb, acT, HDIM, 1.0f / N_NODES);
        // h = relu( relu(BN(t)) @ W2 + b2 )  (bf16 out)
        mm_kernel<HDIM, true, true, true, false, true><<<grid96, 192, 0, stream>>>(buf, W2, b2, acT, hb, nullptr, N_NODES);
    }

    // global add pool
    hipMemsetAsync(g, 0, (size_t)N_GRAPHS * HDIM * 4, stream);
    pool_kernel<<<(N_NODES * 48 + 255) / 256, 256, 0, stream>>>(hb, batch, g, N_NODES);

    // g1 = relu(BN_fc(g) @ Wl + bl), fused stats(g1)
    hipMemsetAsync(statsG, 0, 2 * HDIM * 4, stream);
    colstats_kernel<HDIM><<<64, 2 * HDIM, 0, stream>>>(g, statsG, N_GRAPHS);
    finalize_bn_kernel<<<1, HDIM, 0, stream>>>(statsG, bn_fc_w, bn_fc_b, acG, HDIM, 1.0f / N_GRAPHS);
    hipMemsetAsync(statsG1, 0, 2 * HDIM * 4, stream);
    mm_kernel<HDIM, true, false, true, true, false><<<gridG, 192, 0, stream>>>(g, Wl, bl, acG, g1, statsG1, N_GRAPHS);
    finalize_bn_kernel<<<1, HDIM, 0, stream>>>(statsG1, bn_hid_w, bn_hid_b, acHid, HDIM, 1.0f / N_GRAPHS);

    // logits + log_softmax
    head_kernel<<<2, 256, 0, stream>>>(g1, acHid, Wc, bc, out, N_GRAPHS);
}